// Round 3
// baseline (440.861 us; speedup 1.0000x reference)
//
#include <hip/hip_runtime.h>
#include <math.h>

#define C_CAND 10

// 12-byte vector loads with true 4-byte alignment (rows are 12B-strided,
// so only 4B-aligned). gfx950 global_load_dwordx3 needs only dword alignment.
typedef float vf3 __attribute__((ext_vector_type(3), aligned(4)));
typedef int   vi3 __attribute__((ext_vector_type(3), aligned(4)));
typedef int   v2i __attribute__((ext_vector_type(2)));  // 8B, naturally aligned

// Bit-identical point-triangle "merged distance". Op order mirrors numpy
// exactly; contract(off) forbids FMA fusion (IEEE div/sqrt match numpy).
__device__ __forceinline__ float tri_merged(
    float qx, float qy, float qz,
    float v0x, float v0y, float v0z,
    float v1x, float v1y, float v1z,
    float v2x, float v2y, float v2z)
{
#pragma clang fp contract(off)
    const float e10x = v1x - v0x, e10y = v1y - v0y, e10z = v1z - v0z;
    const float e21x = v2x - v1x, e21y = v2y - v1y, e21z = v2z - v1z;
    const float e02x = v0x - v2x, e02y = v0y - v2y, e02z = v0z - v2z;

    // fN = -cross(e10, e02)
    const float crx = e10y*e02z - e10z*e02y;
    const float cry = e10z*e02x - e10x*e02z;
    const float crz = e10x*e02y - e10y*e02x;
    const float fNx = -crx, fNy = -cry, fNz = -crz;

    const float a0x = qx - v0x, a0y = qy - v0y, a0z = qz - v0z;
    const float a1x = qx - v1x, a1y = qy - v1y, a1z = qz - v1z;
    const float a2x = qx - v2x, a2y = qy - v2y, a2z = qz - v2z;

    const float num_ab = (a0x*e10x + a0y*e10y) + a0z*e10z;
    const float den_ab = fmaxf((e10x*e10x + e10y*e10y) + e10z*e10z, 1e-9f);
    const float uab = num_ab / den_ab;

    const float num_bc = (a1x*e21x + a1y*e21y) + a1z*e21z;
    const float den_bc = fmaxf((e21x*e21x + e21y*e21y) + e21z*e21z, 1e-9f);
    const float ubc = num_bc / den_bc;

    const float num_ca = (a2x*e02x + a2y*e02y) + a2z*e02z;
    const float den_ca = fmaxf((e02x*e02x + e02y*e02y) + e02z*e02z, 1e-9f);
    const float uca = num_ca / den_ca;

    const bool t1 = (uca > 1.0f) && (uab < 0.0f);
    const bool t2 = (uab > 1.0f) && (ubc < 0.0f);
    const bool t3 = (ubc > 1.0f) && (uca < 0.0f);

    // _is_not_above: dot(cross(fN, e), p - v) <= 0
    const float c0x = fNy*e10z - fNz*e10y;
    const float c0y = fNz*e10x - fNx*e10z;
    const float c0z = fNx*e10y - fNy*e10x;
    const bool na0 = ((c0x*a0x + c0y*a0y) + c0z*a0z) <= 0.0f;

    const float c1x = fNy*e21z - fNz*e21y;
    const float c1y = fNz*e21x - fNx*e21z;
    const float c1z = fNx*e21y - fNy*e21x;
    const bool na1 = ((c1x*a1x + c1y*a1y) + c1z*a1z) <= 0.0f;

    const float c2x = fNy*e02z - fNz*e02y;
    const float c2y = fNz*e02x - fNx*e02z;
    const float c2z = fNx*e02y - fNy*e02x;
    const bool na2 = ((c2x*a2x + c2y*a2y) + c2z*a2z) <= 0.0f;

    const bool t4 = (uab >= 0.0f) && (uab <= 1.0f) && na0;
    const bool t5 = (ubc >= 0.0f) && (ubc <= 1.0f) && na1 && !t4;
    const bool t6 = (uca >= 0.0f) && (uca <= 1.0f) && na2 && !t4 && !t5;
    const bool t0 = !(t1 || t2 || t3 || t4 || t5 || t6);

    const float nrm = sqrtf((fNx*fNx + fNy*fNy) + fNz*fNz);
    const float dnm = fmaxf(nrm, 1e-9f);
    const float unx = fNx / dnm;
    const float uny = fNy / dnm;
    const float unz = fNz / dnm;

    const float d0 = (a0x*unx + a0y*uny) + a0z*unz;
    const float d1 = sqrtf((a0x*a0x + a0y*a0y) + a0z*a0z);
    const float d2 = sqrtf((a1x*a1x + a1y*a1y) + a1z*a1z);
    const float d3 = sqrtf((a2x*a2x + a2y*a2y) + a2z*a2z);

    const float p4x = v0x + e10x*uab, p4y = v0y + e10y*uab, p4z = v0z + e10z*uab;
    const float p5x = v1x + e21x*ubc, p5y = v1y + e21y*ubc, p5z = v1z + e21z*ubc;
    const float p6x = v2x + e02x*uca, p6y = v2y + e02y*uca, p6z = v2z + e02z*uca;

    const float g4x = qx - p4x, g4y = qy - p4y, g4z = qz - p4z;
    const float g5x = qx - p5x, g5y = qy - p5y, g5z = qz - p5z;
    const float g6x = qx - p6x, g6y = qy - p6y, g6z = qz - p6z;

    const float d4 = sqrtf((g4x*g4x + g4y*g4y) + g4z*g4z);
    const float d5 = sqrtf((g5x*g5x + g5y*g5y) + g5z*g5z);
    const float d6 = sqrtf((g6x*g6x + g6y*g6y) + g6z*g6z);

    float merged = d0 * (t0 ? 1.0f : 0.0f);
    merged = merged + d1 * (t1 ? 1.0f : 0.0f);
    merged = merged + d2 * (t2 ? 1.0f : 0.0f);
    merged = merged + d3 * (t3 ? 1.0f : 0.0f);
    merged = merged + d4 * (t4 ? 1.0f : 0.0f);
    merged = merged + d5 * (t5 ? 1.0f : 0.0f);
    merged = merged + d6 * (t6 ? 1.0f : 0.0f);
    return merged;
}

// __launch_bounds__(256, 4): cap allocator at ~128 VGPR so we keep
// >=4 waves/SIMD (R2's explicit-array version hit 176 VGPR -> 10% occupancy).
__global__ __launch_bounds__(256, 4) void wootGlobalToLocal_kernel(
    const float* __restrict__ query_xyz,
    const float* __restrict__ temp_verts,
    const int*   __restrict__ faces,
    const int*   __restrict__ cand_ids,
    float*       __restrict__ out_ret,
    float*       __restrict__ out_md,
    int n)
{
    int i = blockIdx.x * blockDim.x + threadIdx.x;
    if (i >= n) return;

    // Streaming traffic is nontemporal: keeps the gather tables (faces 2.4MB
    // + verts 1.2MB) resident in the 4MiB/XCD L2 (proven in R2: 140->30MB).
    const vf3 q = __builtin_nontemporal_load((const vf3*)(query_xyz + 3*i));
    const float qx = q.x, qy = q.y, qz = q.z;

    // cand row: 40B, 8B-aligned -> five nt dwordx2 (was ten scalar loads).
    const v2i* cp = (const v2i*)(cand_ids + i * C_CAND);
    const v2i c0 = __builtin_nontemporal_load(cp + 0);
    const v2i c1 = __builtin_nontemporal_load(cp + 1);
    const v2i c2 = __builtin_nontemporal_load(cp + 2);
    const v2i c3 = __builtin_nontemporal_load(cp + 3);
    const v2i c4 = __builtin_nontemporal_load(cp + 4);
    const int cid[C_CAND] = { c0.x, c0.y, c1.x, c1.y, c2.x,
                              c2.y, c3.x, c3.y, c4.x, c4.y };

    float best_abs = 0.0f;
    float best_md  = 0.0f;
    int   best_f   = 0;

    // Full unroll: cid[] indices constant -> stays in registers.
    // Per candidate: 1 dwordx3 face gather + 3 dwordx3 vert gathers
    // (was 12 scalar gathers) -> ~3x less TA address-processing.
#pragma unroll
    for (int j = 0; j < C_CAND; ++j) {
        const int f = cid[j];
        const vi3 fi = *(const vi3*)(faces + 3*f);
        const vf3 v0 = *(const vf3*)(temp_verts + 3*fi.x);
        const vf3 v1 = *(const vf3*)(temp_verts + 3*fi.y);
        const vf3 v2 = *(const vf3*)(temp_verts + 3*fi.z);

        const float merged = tri_merged(qx, qy, qz,
                                        v0.x, v0.y, v0.z,
                                        v1.x, v1.y, v1.z,
                                        v2.x, v2.y, v2.z);
        const float am = fabsf(merged);
        // strict < keeps FIRST minimum — matches np.argmin tie-break
        if (j == 0 || am < best_abs) {
            best_abs = am;
            best_md  = merged;
            best_f   = f;
        }
    }

    __builtin_nontemporal_store((float)best_f, &out_ret[i]);
    __builtin_nontemporal_store(best_md,       &out_md[i]);
}

extern "C" void kernel_launch(void* const* d_in, const int* in_sizes, int n_in,
                              void* d_out, int out_size, void* d_ws, size_t ws_size,
                              hipStream_t stream) {
    const float* query_xyz  = (const float*)d_in[0];
    const float* temp_verts = (const float*)d_in[1];
    const int*   faces      = (const int*)d_in[2];
    const int*   cand_ids   = (const int*)d_in[3];

    const int n = in_sizes[0] / 3;   // N queries

    float* out_ret = (float*)d_out;  // first N: chosen face id (as float)
    float* out_md  = out_ret + n;    // next N: merged distance

    const int block = 256;
    const int grid  = (n + block - 1) / block;
    wootGlobalToLocal_kernel<<<grid, block, 0, stream>>>(
        query_xyz, temp_verts, faces, cand_ids, out_ret, out_md, n);
}

// Round 4
// 196.930 us; speedup vs baseline: 2.2387x; 2.2387x over previous
//
#include <hip/hip_runtime.h>
#include <math.h>

#define C_CAND 10

// 12-byte vector loads; rows are 12B-strided so only 4B-aligned.
// gfx950 global_load_dwordx3 needs only dword alignment.
typedef float vf3 __attribute__((ext_vector_type(3), aligned(4)));
typedef int   vi3 __attribute__((ext_vector_type(3), aligned(4)));

// Bit-identical point-triangle "merged distance". Op order mirrors numpy
// exactly; contract(off) forbids FMA fusion (IEEE div/sqrt match numpy).
__device__ __forceinline__ float tri_merged(
    float qx, float qy, float qz,
    float v0x, float v0y, float v0z,
    float v1x, float v1y, float v1z,
    float v2x, float v2y, float v2z)
{
#pragma clang fp contract(off)
    const float e10x = v1x - v0x, e10y = v1y - v0y, e10z = v1z - v0z;
    const float e21x = v2x - v1x, e21y = v2y - v1y, e21z = v2z - v1z;
    const float e02x = v0x - v2x, e02y = v0y - v2y, e02z = v0z - v2z;

    // fN = -cross(e10, e02)
    const float crx = e10y*e02z - e10z*e02y;
    const float cry = e10z*e02x - e10x*e02z;
    const float crz = e10x*e02y - e10y*e02x;
    const float fNx = -crx, fNy = -cry, fNz = -crz;

    const float a0x = qx - v0x, a0y = qy - v0y, a0z = qz - v0z;
    const float a1x = qx - v1x, a1y = qy - v1y, a1z = qz - v1z;
    const float a2x = qx - v2x, a2y = qy - v2y, a2z = qz - v2z;

    const float num_ab = (a0x*e10x + a0y*e10y) + a0z*e10z;
    const float den_ab = fmaxf((e10x*e10x + e10y*e10y) + e10z*e10z, 1e-9f);
    const float uab = num_ab / den_ab;

    const float num_bc = (a1x*e21x + a1y*e21y) + a1z*e21z;
    const float den_bc = fmaxf((e21x*e21x + e21y*e21y) + e21z*e21z, 1e-9f);
    const float ubc = num_bc / den_bc;

    const float num_ca = (a2x*e02x + a2y*e02y) + a2z*e02z;
    const float den_ca = fmaxf((e02x*e02x + e02y*e02y) + e02z*e02z, 1e-9f);
    const float uca = num_ca / den_ca;

    const bool t1 = (uca > 1.0f) && (uab < 0.0f);
    const bool t2 = (uab > 1.0f) && (ubc < 0.0f);
    const bool t3 = (ubc > 1.0f) && (uca < 0.0f);

    // _is_not_above: dot(cross(fN, e), p - v) <= 0
    const float c0x = fNy*e10z - fNz*e10y;
    const float c0y = fNz*e10x - fNx*e10z;
    const float c0z = fNx*e10y - fNy*e10x;
    const bool na0 = ((c0x*a0x + c0y*a0y) + c0z*a0z) <= 0.0f;

    const float c1x = fNy*e21z - fNz*e21y;
    const float c1y = fNz*e21x - fNx*e21z;
    const float c1z = fNx*e21y - fNy*e21x;
    const bool na1 = ((c1x*a1x + c1y*a1y) + c1z*a1z) <= 0.0f;

    const float c2x = fNy*e02z - fNz*e02y;
    const float c2y = fNz*e02x - fNx*e02z;
    const float c2z = fNx*e02y - fNy*e02x;
    const bool na2 = ((c2x*a2x + c2y*a2y) + c2z*a2z) <= 0.0f;

    const bool t4 = (uab >= 0.0f) && (uab <= 1.0f) && na0;
    const bool t5 = (ubc >= 0.0f) && (ubc <= 1.0f) && na1 && !t4;
    const bool t6 = (uca >= 0.0f) && (uca <= 1.0f) && na2 && !t4 && !t5;
    const bool t0 = !(t1 || t2 || t3 || t4 || t5 || t6);

    const float nrm = sqrtf((fNx*fNx + fNy*fNy) + fNz*fNz);
    const float dnm = fmaxf(nrm, 1e-9f);
    const float unx = fNx / dnm;
    const float uny = fNy / dnm;
    const float unz = fNz / dnm;

    const float d0 = (a0x*unx + a0y*uny) + a0z*unz;
    const float d1 = sqrtf((a0x*a0x + a0y*a0y) + a0z*a0z);
    const float d2 = sqrtf((a1x*a1x + a1y*a1y) + a1z*a1z);
    const float d3 = sqrtf((a2x*a2x + a2y*a2y) + a2z*a2z);

    const float p4x = v0x + e10x*uab, p4y = v0y + e10y*uab, p4z = v0z + e10z*uab;
    const float p5x = v1x + e21x*ubc, p5y = v1y + e21y*ubc, p5z = v1z + e21z*ubc;
    const float p6x = v2x + e02x*uca, p6y = v2y + e02y*uca, p6z = v2z + e02z*uca;

    const float g4x = qx - p4x, g4y = qy - p4y, g4z = qz - p4z;
    const float g5x = qx - p5x, g5y = qy - p5y, g5z = qz - p5z;
    const float g6x = qx - p6x, g6y = qy - p6y, g6z = qz - p6z;

    const float d4 = sqrtf((g4x*g4x + g4y*g4y) + g4z*g4z);
    const float d5 = sqrtf((g5x*g5x + g5y*g5y) + g5z*g5z);
    const float d6 = sqrtf((g6x*g6x + g6y*g6y) + g6z*g6z);

    float merged = d0 * (t0 ? 1.0f : 0.0f);
    merged = merged + d1 * (t1 ? 1.0f : 0.0f);
    merged = merged + d2 * (t2 ? 1.0f : 0.0f);
    merged = merged + d3 * (t3 ? 1.0f : 0.0f);
    merged = merged + d4 * (t4 ? 1.0f : 0.0f);
    merged = merged + d5 * (t5 ? 1.0f : 0.0f);
    merged = merged + d6 * (t6 ? 1.0f : 0.0f);
    return merged;
}

// Plain __launch_bounds__(256): R1's allocator run gave 32 VGPR / 60% occ.
// NO min-waves clamp, NO private arrays — R3's cid[] array + (256,4) clamp
// produced ~1KB/thread scratch spill (WRITE_SIZE 4MB -> 460MB, 2.7x slower).
__global__ __launch_bounds__(256) void wootGlobalToLocal_kernel(
    const float* __restrict__ query_xyz,
    const float* __restrict__ temp_verts,
    const int*   __restrict__ faces,
    const int*   __restrict__ cand_ids,
    float*       __restrict__ out_ret,
    float*       __restrict__ out_md,
    int n)
{
    int i = blockIdx.x * blockDim.x + threadIdx.x;
    if (i >= n) return;

    // Streaming traffic is nontemporal: keeps the gather tables (faces 2.4MB
    // + verts 1.2MB) resident in the 4MiB/XCD L2 (proven in R2: 140->30MB).
    const vf3 q = __builtin_nontemporal_load((const vf3*)(query_xyz + 3*i));
    const float qx = q.x, qy = q.y, qz = q.z;

    float best_abs = 0.0f;
    float best_md  = 0.0f;
    int   best_f   = 0;

    // Per candidate: 1 scalar cand load + 1 dwordx3 face gather + 3 dwordx3
    // vert gathers = 5 VMEM instrs (R1 had 13 scalar gathers). TA model:
    // ~5*64cyc*10 per wave vs R1's ~8.4k cyc -> ~2.6x less address traffic.
    for (int j = 0; j < C_CAND; ++j) {
        const int f = __builtin_nontemporal_load(&cand_ids[i * C_CAND + j]);

        const vi3 fi = *(const vi3*)(faces + 3*f);
        const int i0 = fi.x, i1 = fi.y, i2 = fi.z;

        const vf3 v0 = *(const vf3*)(temp_verts + 3*i0);
        const vf3 v1 = *(const vf3*)(temp_verts + 3*i1);
        const vf3 v2 = *(const vf3*)(temp_verts + 3*i2);

        const float merged = tri_merged(qx, qy, qz,
                                        v0.x, v0.y, v0.z,
                                        v1.x, v1.y, v1.z,
                                        v2.x, v2.y, v2.z);
        const float am = fabsf(merged);
        // strict < keeps FIRST minimum — matches np.argmin tie-break
        if (j == 0 || am < best_abs) {
            best_abs = am;
            best_md  = merged;
            best_f   = f;
        }
    }

    __builtin_nontemporal_store((float)best_f, &out_ret[i]);
    __builtin_nontemporal_store(best_md,       &out_md[i]);
}

extern "C" void kernel_launch(void* const* d_in, const int* in_sizes, int n_in,
                              void* d_out, int out_size, void* d_ws, size_t ws_size,
                              hipStream_t stream) {
    const float* query_xyz  = (const float*)d_in[0];
    const float* temp_verts = (const float*)d_in[1];
    const int*   faces      = (const int*)d_in[2];
    const int*   cand_ids   = (const int*)d_in[3];

    const int n = in_sizes[0] / 3;   // N queries

    float* out_ret = (float*)d_out;  // first N: chosen face id (as float)
    float* out_md  = out_ret + n;    // next N: merged distance

    const int block = 256;
    const int grid  = (n + block - 1) / block;
    wootGlobalToLocal_kernel<<<grid, block, 0, stream>>>(
        query_xyz, temp_verts, faces, cand_ids, out_ret, out_md, n);
}